// Round 1
// baseline (13144.168 us; speedup 1.0000x reference)
//
#include <hip/hip_runtime.h>
#include <math.h>

#define NB     32
#define NLQ    50
#define NSTEPS 256
#define NEMB   256
#define NHID   512
#define NG4    2048   // 4*NHID
#define NQOUT  256
#define NW     32000

// ---------------------------------------------------------------------------
// Device-scope grid barrier (all blocks co-resident: grid=128 <= 256 CUs,
// block=256 thr, ~35KB LDS -> guaranteed simultaneous residency).
// bar[0] = arrival counter, bar[32] = generation (separate cachelines).
// ---------------------------------------------------------------------------
__device__ __forceinline__ void grid_sync(int* bar, int nblk) {
    __syncthreads();
    if (threadIdx.x == 0) {
        __threadfence();   // release: make h writes visible device-wide
        int* cnt = bar;
        int* gen = bar + 32;
        int g = __hip_atomic_load(gen, __ATOMIC_RELAXED, __HIP_MEMORY_SCOPE_AGENT);
        int a = __hip_atomic_fetch_add(cnt, 1, __ATOMIC_ACQ_REL, __HIP_MEMORY_SCOPE_AGENT);
        if (a == nblk - 1) {
            __hip_atomic_store(cnt, 0, __ATOMIC_RELAXED, __HIP_MEMORY_SCOPE_AGENT);
            __hip_atomic_store(gen, g + 1, __ATOMIC_RELEASE, __HIP_MEMORY_SCOPE_AGENT);
        } else {
            while (__hip_atomic_load(gen, __ATOMIC_ACQUIRE, __HIP_MEMORY_SCOPE_AGENT) == g) {
                __builtin_amdgcn_s_sleep(1);
            }
        }
        __threadfence();   // acquire: invalidate stale L1/L2 before reading h
    }
    __syncthreads();
}

__device__ __forceinline__ float sigm(float x) { return 1.0f / (1.0f + expf(-x)); }

// ---------------------------------------------------------------------------
// Input projection GEMM:  XP[m][j] = b_ih[j]+b_hh[j] + A[m]·w_ih[j]
// A row m (m = b*T + t): first K1 cols = emb[idx[b*idx_stride + t]],
// next K2 cols = q2[b] (decoder only). 64x64 tile, BK=32, 4x4 micro.
// M, N, KT all multiples of tile sizes -> no edge handling.
// ---------------------------------------------------------------------------
template<int K1, int K2, int KT>
__global__ __launch_bounds__(256)
void proj_gemm(const float* __restrict__ emb, const int* __restrict__ idx,
               const float* __restrict__ q2, const float* __restrict__ w_ih,
               const float* __restrict__ b_ih, const float* __restrict__ b_hh,
               float* __restrict__ xp, int T, int idx_stride)
{
    const int BK = 32;
    __shared__ float As[BK][64 + 4];
    __shared__ float Bs[BK][64 + 4];
    const int tid = threadIdx.x;
    const int m0 = blockIdx.y * 64, n0 = blockIdx.x * 64;
    const int tx = tid & 15, ty = tid >> 4;
    const int lr = tid >> 2, lc = tid & 3;

    const int m = m0 + lr;
    const int b = m / T, t = m - b * T;
    const float* arow1 = emb + (size_t)idx[b * idx_stride + t] * K1;
    const float* arow2 = (K2 > 0) ? (q2 + (size_t)b * K2) : nullptr;
    const float* brow  = w_ih + (size_t)(n0 + lr) * KT;

    float acc[4][4] = {};

    for (int k0 = 0; k0 < KT; k0 += BK) {
        const float* asrc = (k0 < K1) ? (arow1 + k0) : (arow2 + (k0 - K1));
        float4 a1 = ((const float4*)asrc)[lc];
        float4 a2 = ((const float4*)asrc)[lc + 4];
        float4 b1 = ((const float4*)(brow + k0))[lc];
        float4 b2 = ((const float4*)(brow + k0))[lc + 4];
        __syncthreads();
        As[lc*4+0][lr] = a1.x; As[lc*4+1][lr] = a1.y; As[lc*4+2][lr] = a1.z; As[lc*4+3][lr] = a1.w;
        As[(lc+4)*4+0][lr] = a2.x; As[(lc+4)*4+1][lr] = a2.y; As[(lc+4)*4+2][lr] = a2.z; As[(lc+4)*4+3][lr] = a2.w;
        Bs[lc*4+0][lr] = b1.x; Bs[lc*4+1][lr] = b1.y; Bs[lc*4+2][lr] = b1.z; Bs[lc*4+3][lr] = b1.w;
        Bs[(lc+4)*4+0][lr] = b2.x; Bs[(lc+4)*4+1][lr] = b2.y; Bs[(lc+4)*4+2][lr] = b2.z; Bs[(lc+4)*4+3][lr] = b2.w;
        __syncthreads();
#pragma unroll
        for (int kk = 0; kk < BK; ++kk) {
            float4 a4 = *(const float4*)&As[kk][tx * 4];
            float4 b4 = *(const float4*)&Bs[kk][ty * 4];
            acc[0][0] += a4.x*b4.x; acc[0][1] += a4.x*b4.y; acc[0][2] += a4.x*b4.z; acc[0][3] += a4.x*b4.w;
            acc[1][0] += a4.y*b4.x; acc[1][1] += a4.y*b4.y; acc[1][2] += a4.y*b4.z; acc[1][3] += a4.y*b4.w;
            acc[2][0] += a4.z*b4.x; acc[2][1] += a4.z*b4.y; acc[2][2] += a4.z*b4.z; acc[2][3] += a4.z*b4.w;
            acc[3][0] += a4.w*b4.x; acc[3][1] += a4.w*b4.y; acc[3][2] += a4.w*b4.z; acc[3][3] += a4.w*b4.w;
        }
    }

    const int nb = n0 + ty * 4;
    float4 bias;
    bias.x = b_ih[nb+0] + b_hh[nb+0];
    bias.y = b_ih[nb+1] + b_hh[nb+1];
    bias.z = b_ih[nb+2] + b_hh[nb+2];
    bias.w = b_ih[nb+3] + b_hh[nb+3];
#pragma unroll
    for (int i = 0; i < 4; ++i) {
        int mm = m0 + tx * 4 + i;
        float4 v;
        v.x = acc[i][0] + bias.x; v.y = acc[i][1] + bias.y;
        v.z = acc[i][2] + bias.z; v.w = acc[i][3] + bias.w;
        *(float4*)&xp[(size_t)mm * NG4 + nb] = v;
    }
}

// ---------------------------------------------------------------------------
// Persistent LSTM scan. 128 blocks x 256 thr. Block bid owns hidden slice
// k0=4*bid (4 units) and the 16 matching w_hh rows (i/f/g/o), LDS-resident.
// h double-buffered in global (h0b/h1b); c in registers for threads tid<128.
// One grid barrier per step.
// ---------------------------------------------------------------------------
__global__ __launch_bounds__(256, 1)
void lstm_scan(const float* __restrict__ xp, const float* __restrict__ w_hh,
               float* __restrict__ h0b, float* __restrict__ h1b,
               float* __restrict__ cg, float* __restrict__ hsout,
               int T, int* bar)
{
    __shared__ float w_s[16][NHID];     // 32 KB
    __shared__ float g_s[16][33];       // gate values [j_local][b]
    const int tid = threadIdx.x, bid = blockIdx.x;
    const int k0 = bid * 4;

    // preload w_hh rows: j_local l -> j_global = (l>>2)*512 + k0 + (l&3)
    {
        const int l = tid >> 4, c = tid & 15;
        const int jgl = ((l >> 2) * NHID) + k0 + (l & 3);
        const float4* src = (const float4*)(w_hh + (size_t)jgl * NHID);
        float4* dst = (float4*)&w_s[l][0];
#pragma unroll
        for (int q = 0; q < 8; ++q) dst[c + 16 * q] = src[c + 16 * q];
    }

    const int b  = tid & 31;
    const int jg = tid >> 5;                              // [0,8): 2 rows each
    const int jga = (jg >> 2) * NHID + k0 + (jg & 3);         // rows 0..7  (i,f)
    const int jgb = ((jg + 8) >> 2) * NHID + k0 + ((jg + 8) & 3); // rows 8..15 (g,o)
    const int kl = tid >> 5;                              // phase2: tid<128

    float c_reg = 0.0f;
    if (tid < 128) c_reg = cg[b * NHID + k0 + kl];
    __syncthreads();

    for (int t = 0; t < T; ++t) {
        const float* hin  = (t & 1) ? h1b : h0b;
        float*       hout = (t & 1) ? h0b : h1b;

        size_t xrow = (size_t)(b * T + t) * NG4;
        float acc0 = xp[xrow + jga];
        float acc1 = xp[xrow + jgb];

        const float4* h4p = (const float4*)(hin + b * NHID);
        const float4* wa  = (const float4*)&w_s[jg][0];
        const float4* wb  = (const float4*)&w_s[jg + 8][0];
#pragma unroll 4
        for (int kc = 0; kc < NHID / 4; ++kc) {
            float4 h4  = h4p[kc];
            float4 w4a = wa[kc];
            float4 w4b = wb[kc];
            acc0 += h4.x*w4a.x + h4.y*w4a.y + h4.z*w4a.z + h4.w*w4a.w;
            acc1 += h4.x*w4b.x + h4.y*w4b.y + h4.z*w4b.z + h4.w*w4b.w;
        }
        g_s[jg][b]     = acc0;
        g_s[jg + 8][b] = acc1;
        __syncthreads();

        if (tid < 128) {
            float iv = sigm(g_s[kl][b]);
            float fv = sigm(g_s[4 + kl][b]);
            float gv = tanhf(g_s[8 + kl][b]);
            float ov = sigm(g_s[12 + kl][b]);
            c_reg = fv * c_reg + iv * gv;
            float hv = ov * tanhf(c_reg);
            hout[b * NHID + k0 + kl] = hv;
            if (hsout) hsout[(size_t)t * (NB * NHID) + b * NHID + k0 + kl] = hv;
        }
        grid_sync(bar, gridDim.x);
    }
    if (tid < 128) cg[b * NHID + k0 + kl] = c_reg;
}

// ---------------------------------------------------------------------------
// q_out[b][o] = q_lin_b[o] + h[b]·q_lin_w[o]
// ---------------------------------------------------------------------------
__global__ __launch_bounds__(256)
void qout_kernel(const float* __restrict__ h, const float* __restrict__ qw,
                 const float* __restrict__ qb, float* __restrict__ qo)
{
    __shared__ float hsh[NHID];
    const int b = blockIdx.x, o = threadIdx.x;
    for (int k = o; k < NHID; k += 256) hsh[k] = h[b * NHID + k];
    __syncthreads();
    float acc = qb[o];
    const float4* w4 = (const float4*)(qw + (size_t)o * NHID);
#pragma unroll 4
    for (int kc = 0; kc < NHID / 4; ++kc) {
        float4 w = w4[kc];
        acc += hsh[4*kc]*w.x + hsh[4*kc+1]*w.y + hsh[4*kc+2]*w.z + hsh[4*kc+3]*w.w;
    }
    qo[b * NQOUT + o] = acc;
}

// ---------------------------------------------------------------------------
// Output projection: out[b][w][t] = lin_b[w] + hs[t][b]·lin_w[w]
// Per block: 64 w x 64 t tile for one b. Grid (t-tiles=4, b=32, w-tiles=500):
// w-tile slowest so concurrent blocks share the same lin_w rows in L2.
// ---------------------------------------------------------------------------
__global__ __launch_bounds__(256)
void out_gemm(const float* __restrict__ lw, const float* __restrict__ lb,
              const float* __restrict__ hs, float* __restrict__ out)
{
    const int BK = 32;
    __shared__ float As[BK][64 + 4];   // lin_w tile [k][w]
    __shared__ float Bs[BK][64 + 4];   // hs tile    [k][t]
    const int tid = threadIdx.x;
    const int t0 = blockIdx.x * 64;
    const int zb = blockIdx.y;
    const int w0 = blockIdx.z * 64;
    const int tx = tid & 15, ty = tid >> 4;
    const int lr = tid >> 2, lc = tid & 3;

    const float* arow = lw + (size_t)(w0 + lr) * NHID;
    const float* brow = hs + ((size_t)(t0 + lr) * NB + zb) * NHID;

    float acc[4][4] = {};

    for (int k0 = 0; k0 < NHID; k0 += BK) {
        float4 a1 = ((const float4*)(arow + k0))[lc];
        float4 a2 = ((const float4*)(arow + k0))[lc + 4];
        float4 b1 = ((const float4*)(brow + k0))[lc];
        float4 b2 = ((const float4*)(brow + k0))[lc + 4];
        __syncthreads();
        As[lc*4+0][lr] = a1.x; As[lc*4+1][lr] = a1.y; As[lc*4+2][lr] = a1.z; As[lc*4+3][lr] = a1.w;
        As[(lc+4)*4+0][lr] = a2.x; As[(lc+4)*4+1][lr] = a2.y; As[(lc+4)*4+2][lr] = a2.z; As[(lc+4)*4+3][lr] = a2.w;
        Bs[lc*4+0][lr] = b1.x; Bs[lc*4+1][lr] = b1.y; Bs[lc*4+2][lr] = b1.z; Bs[lc*4+3][lr] = b1.w;
        Bs[(lc+4)*4+0][lr] = b2.x; Bs[(lc+4)*4+1][lr] = b2.y; Bs[(lc+4)*4+2][lr] = b2.z; Bs[(lc+4)*4+3][lr] = b2.w;
        __syncthreads();
#pragma unroll
        for (int kk = 0; kk < BK; ++kk) {
            float4 a4 = *(const float4*)&As[kk][tx * 4];
            float4 b4 = *(const float4*)&Bs[kk][ty * 4];
            acc[0][0] += a4.x*b4.x; acc[0][1] += a4.x*b4.y; acc[0][2] += a4.x*b4.z; acc[0][3] += a4.x*b4.w;
            acc[1][0] += a4.y*b4.x; acc[1][1] += a4.y*b4.y; acc[1][2] += a4.y*b4.z; acc[1][3] += a4.y*b4.w;
            acc[2][0] += a4.z*b4.x; acc[2][1] += a4.z*b4.y; acc[2][2] += a4.z*b4.z; acc[2][3] += a4.z*b4.w;
            acc[3][0] += a4.w*b4.x; acc[3][1] += a4.w*b4.y; acc[3][2] += a4.w*b4.z; acc[3][3] += a4.w*b4.w;
        }
    }

#pragma unroll
    for (int i = 0; i < 4; ++i) {
        int w = w0 + tx * 4 + i;
        float bias = lb[w];
        float4 v;
        v.x = acc[i][0] + bias; v.y = acc[i][1] + bias;
        v.z = acc[i][2] + bias; v.w = acc[i][3] + bias;
        *(float4*)&out[((size_t)zb * NW + w) * NSTEPS + t0 + ty * 4] = v;
    }
}

// ---------------------------------------------------------------------------
extern "C" void kernel_launch(void* const* d_in, const int* in_sizes, int n_in,
                              void* d_out, int out_size, void* d_ws, size_t ws_size,
                              hipStream_t stream)
{
    const int*   question = (const int*)d_in[0];
    const int*   answer   = (const int*)d_in[1];
    const float* q_emb_w  = (const float*)d_in[2];
    const float* a_emb_w  = (const float*)d_in[3];
    const float* q_w_ih   = (const float*)d_in[4];
    const float* q_w_hh   = (const float*)d_in[5];
    const float* q_b_ih   = (const float*)d_in[6];
    const float* q_b_hh   = (const float*)d_in[7];
    const float* q_lin_w  = (const float*)d_in[8];
    const float* q_lin_b  = (const float*)d_in[9];
    const float* a_w_ih   = (const float*)d_in[10];
    const float* a_w_hh   = (const float*)d_in[11];
    const float* a_b_ih   = (const float*)d_in[12];
    const float* a_b_hh   = (const float*)d_in[13];
    const float* lin_w    = (const float*)d_in[14];
    const float* lin_b    = (const float*)d_in[15];
    float* out = (float*)d_out;

    // workspace layout (floats)
    float* ws  = (float*)d_ws;
    float* hs  = ws;                        // 256*32*512 = 4,194,304
    float* h0b = ws + 4194304;              // 16384
    float* h1b = h0b + 16384;               // 16384
    float* cg  = h1b + 16384;               // 16384
    float* qo  = cg + 16384;                // 8192
    int*   bar = (int*)(qo + 8192);         // 64 ints

    // scratch inside d_out (overwritten by out_gemm only after last read)
    float* XA = out;                        // 32*256*2048 = 16,777,216 floats
    float* XQ = out + 16777216;             // 32*50*2048  =  3,276,800 floats

    // ws is poisoned 0xAA before every launch: zero h0/h1/c and the barrier
    hipMemsetAsync(h0b, 0, (size_t)(16384 * 3) * sizeof(float), stream);
    hipMemsetAsync(bar, 0, 256, stream);

    // 1) encoder input projection: [1600 x 2048], K=256
    proj_gemm<NEMB, 0, NEMB><<<dim3(32, 25), 256, 0, stream>>>(
        q_emb_w, question, nullptr, q_w_ih, q_b_ih, q_b_hh, XQ, NLQ, NLQ);

    // 2) encoder LSTM scan (50 steps); final h -> h0b, final c -> cg
    lstm_scan<<<128, 256, 0, stream>>>(XQ, q_w_hh, h0b, h1b, cg, nullptr, NLQ, bar);

    // 3) q_out = h @ q_lin_w^T + q_lin_b
    qout_kernel<<<32, 256, 0, stream>>>(h0b, q_lin_w, q_lin_b, qo);

    // 4) decoder input projection: [8192 x 2048], K=512 (emb || q_out), note
    //    answer row stride is STEPS+1 = 257
    proj_gemm<NEMB, NQOUT, NHID><<<dim3(32, 128), 256, 0, stream>>>(
        a_emb_w, answer, qo, a_w_ih, a_b_ih, a_b_hh, XA, NSTEPS, NSTEPS + 1);

    // 5) decoder LSTM scan (256 steps), writes hs[t][b][k]
    lstm_scan<<<128, 256, 0, stream>>>(XA, a_w_hh, h0b, h1b, cg, hs, NSTEPS, bar);

    // 6) output projection -> d_out[b][w][t]
    out_gemm<<<dim3(4, 32, 500), 256, 0, stream>>>(lin_w, lin_b, hs, out);
}